// Round 1
// baseline (361.088 us; speedup 1.0000x reference)
//
#include <hip/hip_runtime.h>

#define NB 8
#define NT 2048
#define NC 1024
#define NH 64

static __device__ __forceinline__ float4 ldf4(const float* p) {
  return *reinterpret_cast<const float4*>(p);
}
static __device__ __forceinline__ void stf4(float* p, float4 v) {
  *reinterpret_cast<float4*>(p) = v;
}

// ---------------------------------------------------------------------------
// Kernel 1: q,k,v = x @ {Wq,Wk,Wv}.  x:[16384,1024] f32, W:[1024,64] f32.
// Block: 32 rows of x, all 192 output cols (q|k|v). 256 threads = 16x16.
// ---------------------------------------------------------------------------
__global__ __launch_bounds__(256, 2) void qkv_proj_kernel(
    const float* __restrict__ x, const float* __restrict__ Wq,
    const float* __restrict__ Wk, const float* __restrict__ Wv,
    float* __restrict__ q, float* __restrict__ k, float* __restrict__ v) {
  __shared__ float xs[32][68];    // 32 rows x 64 c-chunk, pad 68
  __shared__ float bs[64][196];   // 64 c x 192 cols (q|k|v), pad 196
  const int tid = threadIdx.x;
  const int row0 = blockIdx.x * 32;
  const int tq = tid >> 4;   // 0..15 -> rows tq*2, tq*2+1
  const int tk = tid & 15;   // 0..15 -> cols tk*12 .. tk*12+11
  float acc[2][12];
#pragma unroll
  for (int i = 0; i < 2; ++i)
#pragma unroll
    for (int j = 0; j < 12; ++j) acc[i][j] = 0.f;

  for (int c0 = 0; c0 < NC; c0 += 64) {
    // stage x tile: 32x64 f32 = 512 float4, 2 per thread (coalesced)
#pragma unroll
    for (int it = 0; it < 2; ++it) {
      int f = tid + it * 256;
      int r = f >> 4, c4 = (f & 15) * 4;
      stf4(&xs[r][c4], ldf4(&x[(row0 + r) * NC + c0 + c4]));
    }
    // stage W tile: 64x192 f32 = 3072 float4, 12 per thread (coalesced per W)
#pragma unroll
    for (int it = 0; it < 12; ++it) {
      int f = tid + it * 256;
      int kk = f / 48, c4 = f % 48;
      int mat = c4 >> 4, h4 = (c4 & 15) * 4;
      const float* W = (mat == 0) ? Wq : (mat == 1) ? Wk : Wv;
      stf4(&bs[kk][mat * 64 + h4], ldf4(&W[(c0 + kk) * NH + h4]));
    }
    __syncthreads();
#pragma unroll 8
    for (int kk = 0; kk < 64; ++kk) {
      float a0 = xs[tq * 2 + 0][kk];
      float a1 = xs[tq * 2 + 1][kk];
      float4 b0 = ldf4(&bs[kk][tk * 12 + 0]);
      float4 b1 = ldf4(&bs[kk][tk * 12 + 4]);
      float4 b2 = ldf4(&bs[kk][tk * 12 + 8]);
      acc[0][0] += a0 * b0.x;  acc[0][1] += a0 * b0.y;
      acc[0][2] += a0 * b0.z;  acc[0][3] += a0 * b0.w;
      acc[0][4] += a0 * b1.x;  acc[0][5] += a0 * b1.y;
      acc[0][6] += a0 * b1.z;  acc[0][7] += a0 * b1.w;
      acc[0][8] += a0 * b2.x;  acc[0][9] += a0 * b2.y;
      acc[0][10] += a0 * b2.z; acc[0][11] += a0 * b2.w;
      acc[1][0] += a1 * b0.x;  acc[1][1] += a1 * b0.y;
      acc[1][2] += a1 * b0.z;  acc[1][3] += a1 * b0.w;
      acc[1][4] += a1 * b1.x;  acc[1][5] += a1 * b1.y;
      acc[1][6] += a1 * b1.z;  acc[1][7] += a1 * b1.w;
      acc[1][8] += a1 * b2.x;  acc[1][9] += a1 * b2.y;
      acc[1][10] += a1 * b2.z; acc[1][11] += a1 * b2.w;
    }
    __syncthreads();
  }
#pragma unroll
  for (int i = 0; i < 2; ++i) {
    int row = row0 + tq * 2 + i;
#pragma unroll
    for (int j = 0; j < 12; ++j) {
      int col = tk * 12 + j;
      float val = acc[i][j];
      if (col < 64)       q[row * NH + col] = val;
      else if (col < 128) k[row * NH + (col - 64)] = val;
      else                v[row * NH + (col - 128)] = val;
    }
  }
}

// ---------------------------------------------------------------------------
// Kernel 2: causal flash attention, fp32. Block = one batch x 32 q-rows.
// 256 threads = 16x16: tq -> 2 q-rows; tk -> 4 keys (s=16j+tk) / 4 h cols.
// k/v LDS rows padded to 76 (16B-aligned float4, <=2-way bank conflicts).
// ---------------------------------------------------------------------------
__global__ __launch_bounds__(256, 2) void attn_kernel(
    const float* __restrict__ q, const float* __restrict__ k,
    const float* __restrict__ v, float* __restrict__ out) {
  __shared__ float qs[32][68];
  __shared__ float ks[64][76];
  __shared__ float vs[64][76];
  __shared__ float ps[32][68];
  const int tid = threadIdx.x;
  const int qt = blockIdx.x;   // 0..63
  const int b = blockIdx.y;    // 0..7
  const int qrow0 = qt * 32;
  const int tq = tid >> 4;
  const int tk = tid & 15;
  const int r0 = tq * 2, r1 = tq * 2 + 1;

  // stage q tile, pre-scaled by 1/sqrt(64)
#pragma unroll
  for (int it = 0; it < 2; ++it) {
    int f = tid + it * 256;
    int r = f >> 4, c4 = (f & 15) * 4;
    float4 val = ldf4(&q[(size_t)(b * NT + qrow0 + r) * NH + c4]);
    val.x *= 0.125f; val.y *= 0.125f; val.z *= 0.125f; val.w *= 0.125f;
    stf4(&qs[r][c4], val);
  }

  float m0 = -1e30f, m1 = -1e30f, l0 = 0.f, l1 = 0.f;
  float o0[4] = {0.f, 0.f, 0.f, 0.f}, o1[4] = {0.f, 0.f, 0.f, 0.f};

  const int nkb = (qrow0 + 31) / 64 + 1;   // causal: only key blocks <= diag
  for (int kb = 0; kb < nkb; ++kb) {
    const int s0 = kb * 64;
    // stage k,v tiles (coalesced float4)
#pragma unroll
    for (int it = 0; it < 4; ++it) {
      int f = tid + it * 256;
      int r = f >> 4, c4 = (f & 15) * 4;
      stf4(&ks[r][c4], ldf4(&k[(size_t)(b * NT + s0 + r) * NH + c4]));
      stf4(&vs[r][c4], ldf4(&v[(size_t)(b * NT + s0 + r) * NH + c4]));
    }
    __syncthreads();

    // S = q @ k^T (scaled already), this thread: 2 rows x 4 keys
    float sa0[4] = {0.f, 0.f, 0.f, 0.f};
    float sa1[4] = {0.f, 0.f, 0.f, 0.f};
#pragma unroll
    for (int h4 = 0; h4 < 16; ++h4) {
      float4 q0 = ldf4(&qs[r0][h4 * 4]);
      float4 q1 = ldf4(&qs[r1][h4 * 4]);
#pragma unroll
      for (int j = 0; j < 4; ++j) {
        float4 kv = ldf4(&ks[16 * j + tk][h4 * 4]);
        sa0[j] += q0.x * kv.x + q0.y * kv.y + q0.z * kv.z + q0.w * kv.w;
        sa1[j] += q1.x * kv.x + q1.y * kv.y + q1.z * kv.z + q1.w * kv.w;
      }
    }
    // causal mask
    const int qg0 = qrow0 + r0, qg1 = qrow0 + r1;
#pragma unroll
    for (int j = 0; j < 4; ++j) {
      int kg = s0 + 16 * j + tk;
      if (kg > qg0) sa0[j] = -1e30f;
      if (kg > qg1) sa1[j] = -1e30f;
    }
    // online softmax: row max across 16 tk-lanes (within-wave shfl)
    float rm0 = fmaxf(fmaxf(sa0[0], sa0[1]), fmaxf(sa0[2], sa0[3]));
    float rm1 = fmaxf(fmaxf(sa1[0], sa1[1]), fmaxf(sa1[2], sa1[3]));
#pragma unroll
    for (int d = 1; d < 16; d <<= 1) {
      rm0 = fmaxf(rm0, __shfl_xor(rm0, d));
      rm1 = fmaxf(rm1, __shfl_xor(rm1, d));
    }
    float mn0 = fmaxf(m0, rm0), mn1 = fmaxf(m1, rm1);
    float a0 = __expf(m0 - mn0), a1 = __expf(m1 - mn1);
    m0 = mn0; m1 = mn1;
    float rs0 = 0.f, rs1 = 0.f;
#pragma unroll
    for (int j = 0; j < 4; ++j) {
      sa0[j] = __expf(sa0[j] - mn0); rs0 += sa0[j];
      sa1[j] = __expf(sa1[j] - mn1); rs1 += sa1[j];
    }
#pragma unroll
    for (int d = 1; d < 16; d <<= 1) {
      rs0 += __shfl_xor(rs0, d);
      rs1 += __shfl_xor(rs1, d);
    }
    l0 = l0 * a0 + rs0;
    l1 = l1 * a1 + rs1;
    // share P via LDS for the PV step
#pragma unroll
    for (int j = 0; j < 4; ++j) {
      ps[r0][16 * j + tk] = sa0[j];
      ps[r1][16 * j + tk] = sa1[j];
    }
#pragma unroll
    for (int h = 0; h < 4; ++h) { o0[h] *= a0; o1[h] *= a1; }
    __syncthreads();

    // O += P @ V, this thread: 2 rows x 4 h-cols (h = tk*4..+3)
#pragma unroll
    for (int s4 = 0; s4 < 16; ++s4) {
      float4 p0 = ldf4(&ps[r0][s4 * 4]);
      float4 p1 = ldf4(&ps[r1][s4 * 4]);
      float4 v0 = ldf4(&vs[s4 * 4 + 0][tk * 4]);
      float4 v1 = ldf4(&vs[s4 * 4 + 1][tk * 4]);
      float4 v2 = ldf4(&vs[s4 * 4 + 2][tk * 4]);
      float4 v3 = ldf4(&vs[s4 * 4 + 3][tk * 4]);
      o0[0] += p0.x * v0.x + p0.y * v1.x + p0.z * v2.x + p0.w * v3.x;
      o0[1] += p0.x * v0.y + p0.y * v1.y + p0.z * v2.y + p0.w * v3.y;
      o0[2] += p0.x * v0.z + p0.y * v1.z + p0.z * v2.z + p0.w * v3.z;
      o0[3] += p0.x * v0.w + p0.y * v1.w + p0.z * v2.w + p0.w * v3.w;
      o1[0] += p1.x * v0.x + p1.y * v1.x + p1.z * v2.x + p1.w * v3.x;
      o1[1] += p1.x * v0.y + p1.y * v1.y + p1.z * v2.y + p1.w * v3.y;
      o1[2] += p1.x * v0.z + p1.y * v1.z + p1.z * v2.z + p1.w * v3.z;
      o1[3] += p1.x * v0.w + p1.y * v1.w + p1.z * v2.w + p1.w * v3.w;
    }
    __syncthreads();
  }

  float inv0 = 1.f / l0, inv1 = 1.f / l1;
  float4 w0 = {o0[0] * inv0, o0[1] * inv0, o0[2] * inv0, o0[3] * inv0};
  float4 w1 = {o1[0] * inv1, o1[1] * inv1, o1[2] * inv1, o1[3] * inv1};
  stf4(&out[(size_t)(b * NT + qrow0 + r0) * NH + tk * 4], w0);
  stf4(&out[(size_t)(b * NT + qrow0 + r1) * NH + tk * 4], w1);
}

extern "C" void kernel_launch(void* const* d_in, const int* in_sizes, int n_in,
                              void* d_out, int out_size, void* d_ws, size_t ws_size,
                              hipStream_t stream) {
  const float* x  = (const float*)d_in[0];
  const float* Wq = (const float*)d_in[1];
  const float* Wk = (const float*)d_in[2];
  const float* Wv = (const float*)d_in[3];
  float* out = (float*)d_out;

  // workspace: q,k,v each [8*2048, 64] fp32 = 4 MB -> 12 MB total
  float* q = (float*)d_ws;
  float* k = q + (size_t)NB * NT * NH;
  float* v = k + (size_t)NB * NT * NH;

  qkv_proj_kernel<<<dim3(NB * NT / 32), dim3(256), 0, stream>>>(x, Wq, Wk, Wv, q, k, v);
  attn_kernel<<<dim3(NT / 32, NB), dim3(256), 0, stream>>>(q, k, v, out);
}

// Round 2
// 63.210 us; speedup vs baseline: 5.7125x; 5.7125x over previous
//
#include <hip/hip_runtime.h>

#define NB 8
#define NT 2048
#define NC 1024
#define NH 64

typedef __bf16 bf16x8 __attribute__((ext_vector_type(8)));
typedef float f32x4 __attribute__((ext_vector_type(4)));

static __device__ __forceinline__ float4 ldf4(const float* p) {
  return *reinterpret_cast<const float4*>(p);
}
static __device__ __forceinline__ unsigned pack_bf2(float a, float b) {
  unsigned short ua = __builtin_bit_cast(unsigned short, (__bf16)a);
  unsigned short ub = __builtin_bit_cast(unsigned short, (__bf16)b);
  return (unsigned)ua | ((unsigned)ub << 16);
}

// ---------------------------------------------------------------------------
// Kernel A: Wt[192][1024] bf16 = transpose+convert of Wq|Wk|Wv (fp32 [1024][64]).
// Grid: 48 blocks (3 mats x 16 k-tiles), 256 threads.
// ---------------------------------------------------------------------------
__global__ __launch_bounds__(256) void wt_kernel(
    const float* __restrict__ Wq, const float* __restrict__ Wk,
    const float* __restrict__ Wv, __bf16* __restrict__ wt) {
  __shared__ __bf16 tl[64][72];  // [h][k], rows 144B (16B-aligned, 2-way banks)
  const int tid = threadIdx.x;
  const int mat = blockIdx.x >> 4;
  const int k0 = (blockIdx.x & 15) * 64;
  const float* W = (mat == 0) ? Wq : (mat == 1) ? Wk : Wv;
#pragma unroll
  for (int it = 0; it < 4; ++it) {
    int f = tid + it * 256;
    int kk = f >> 4, c4 = (f & 15) * 4;
    float4 w = ldf4(&W[(k0 + kk) * NH + c4]);
    tl[c4 + 0][kk] = (__bf16)w.x;
    tl[c4 + 1][kk] = (__bf16)w.y;
    tl[c4 + 2][kk] = (__bf16)w.z;
    tl[c4 + 3][kk] = (__bf16)w.w;
  }
  __syncthreads();
#pragma unroll
  for (int it = 0; it < 2; ++it) {
    int f = tid + it * 256;
    int h = f >> 3, k8 = (f & 7) * 8;
    *reinterpret_cast<bf16x8*>(&wt[(mat * 64 + h) * NC + k0 + k8]) =
        *reinterpret_cast<const bf16x8*>(&tl[h][k8]);
  }
}

// ---------------------------------------------------------------------------
// Kernel B: q,k,v (bf16) = x @ W via MFMA. 256 blocks x 512 thr (8 waves).
// BM=64, BN=192, BK=64 (2 MFMA k-steps). Wave w: rows (w>>2)*32 + [0,32),
// cols (w&3)*48 + [0,48). Reg-double-buffered staging. q pre-scaled by 1/8.
// ---------------------------------------------------------------------------
__global__ __launch_bounds__(512, 2) void qkv_mfma_kernel(
    const float* __restrict__ x, const __bf16* __restrict__ wt,
    __bf16* __restrict__ qb, __bf16* __restrict__ kb, __bf16* __restrict__ vb) {
  __shared__ __bf16 As[64][72];    // [row][k]
  __shared__ __bf16 Bs[192][72];   // [col][k]
  const int tid = threadIdx.x;
  const int lane = tid & 63;
  const int w = tid >> 6;
  const int row0 = blockIdx.x * 64;
  const int rsub = (w >> 2) * 32;
  const int csub = (w & 3) * 48;
  const int l15 = lane & 15, lg = lane >> 4;

  f32x4 acc[2][3];
#pragma unroll
  for (int i = 0; i < 2; ++i)
#pragma unroll
    for (int j = 0; j < 3; ++j) acc[i][j] = (f32x4){0.f, 0.f, 0.f, 0.f};

  float4 areg[2];
  bf16x8 breg[3];
  // prologue: prefetch chunk 0
#pragma unroll
  for (int it = 0; it < 2; ++it) {
    int f = tid + it * 512;
    int r = f >> 4, k4 = (f & 15) * 4;
    areg[it] = ldf4(&x[(row0 + r) * NC + k4]);
  }
#pragma unroll
  for (int it = 0; it < 3; ++it) {
    int f = tid + it * 512;
    int col = f >> 3, k8 = (f & 7) * 8;
    breg[it] = *reinterpret_cast<const bf16x8*>(&wt[col * NC + k8]);
  }

  for (int ch = 0; ch < 16; ++ch) {
    // write staged regs to LDS
#pragma unroll
    for (int it = 0; it < 2; ++it) {
      int f = tid + it * 512;
      int r = f >> 4, k4 = (f & 15) * 4;
      uint2 u = {pack_bf2(areg[it].x, areg[it].y), pack_bf2(areg[it].z, areg[it].w)};
      *reinterpret_cast<uint2*>(&As[r][k4]) = u;
    }
#pragma unroll
    for (int it = 0; it < 3; ++it) {
      int f = tid + it * 512;
      int col = f >> 3, k8 = (f & 7) * 8;
      *reinterpret_cast<bf16x8*>(&Bs[col][k8]) = breg[it];
    }
    __syncthreads();
    // prefetch chunk ch+1 (overlaps with MFMA below)
    if (ch < 15) {
      const int k0n = (ch + 1) * 64;
#pragma unroll
      for (int it = 0; it < 2; ++it) {
        int f = tid + it * 512;
        int r = f >> 4, k4 = (f & 15) * 4;
        areg[it] = ldf4(&x[(row0 + r) * NC + k0n + k4]);
      }
#pragma unroll
      for (int it = 0; it < 3; ++it) {
        int f = tid + it * 512;
        int col = f >> 3, k8 = (f & 7) * 8;
        breg[it] = *reinterpret_cast<const bf16x8*>(&wt[col * NC + k0n + k8]);
      }
    }
    // 2 MFMA k-steps over the staged BK=64
#pragma unroll
    for (int kk = 0; kk < 2; ++kk) {
      bf16x8 af[2], bfr[3];
#pragma unroll
      for (int rt = 0; rt < 2; ++rt)
        af[rt] = *reinterpret_cast<const bf16x8*>(&As[rsub + rt * 16 + l15][kk * 32 + lg * 8]);
#pragma unroll
      for (int nt = 0; nt < 3; ++nt)
        bfr[nt] = *reinterpret_cast<const bf16x8*>(&Bs[csub + nt * 16 + l15][kk * 32 + lg * 8]);
#pragma unroll
      for (int rt = 0; rt < 2; ++rt)
#pragma unroll
        for (int nt = 0; nt < 3; ++nt)
          acc[rt][nt] = __builtin_amdgcn_mfma_f32_16x16x32_bf16(af[rt], bfr[nt], acc[rt][nt], 0, 0, 0);
    }
    __syncthreads();
  }

  // epilogue: D layout col=l&15, row=(l>>4)*4+reg
#pragma unroll
  for (int rt = 0; rt < 2; ++rt) {
#pragma unroll
    for (int nt = 0; nt < 3; ++nt) {
      int colb = csub + nt * 16 + l15;
      int mat = colb >> 6, h = colb & 63;
      __bf16* dst = (mat == 0) ? qb : (mat == 1) ? kb : vb;
      float scale = (mat == 0) ? 0.125f : 1.0f;  // pre-scale q by 1/sqrt(64)
#pragma unroll
      for (int r = 0; r < 4; ++r) {
        int row = row0 + rsub + rt * 16 + lg * 4 + r;
        dst[row * NH + h] = (__bf16)(acc[rt][nt][r] * scale);
      }
    }
  }
}

// ---------------------------------------------------------------------------
// Kernel C: vt[8][64][2048] bf16 = per-batch transpose of v.
// Grid: dim3(32, 8), 256 threads; 64x64 tiles through LDS.
// ---------------------------------------------------------------------------
__global__ __launch_bounds__(256) void vt_kernel(const __bf16* __restrict__ vb,
                                                 __bf16* __restrict__ vt) {
  __shared__ __bf16 tl[64][72];
  const int tid = threadIdx.x;
  const int b = blockIdx.y;
  const int t0 = blockIdx.x * 64;
  const size_t bT = (size_t)b * NT;
#pragma unroll
  for (int it = 0; it < 2; ++it) {
    int f = tid + it * 256;
    int r = f >> 3, h8 = (f & 7) * 8;
    bf16x8 vv = *reinterpret_cast<const bf16x8*>(&vb[(bT + t0 + r) * NH + h8]);
#pragma unroll
    for (int i = 0; i < 8; ++i) tl[h8 + i][r] = vv[i];
  }
  __syncthreads();
#pragma unroll
  for (int it = 0; it < 2; ++it) {
    int f = tid + it * 256;
    int h = f >> 3, t8 = (f & 7) * 8;
    *reinterpret_cast<bf16x8*>(&vt[((size_t)b * NH + h) * NT + t0 + t8]) =
        *reinterpret_cast<const bf16x8*>(&tl[h][t8]);
  }
}

// ---------------------------------------------------------------------------
// Kernel D: causal flash attention via MFMA, intra-block KV split.
// Grid: dim3(64, 8) (qt reversed so heavy tiles launch first), 256 thr = 4 waves.
// Each wave: all 32 q-rows, KV chunks c = w, w+4, ... (KVBLK=64).
// S^T = mfma(K, Q): per-lane row-local softmax; P via wave-private LDS; PV via
// vT global frags. End: 4-way LDS combine (m, l, O partials).
// ---------------------------------------------------------------------------
__global__ __launch_bounds__(256, 2) void attn_mfma_kernel(
    const __bf16* __restrict__ qb, const __bf16* __restrict__ kb,
    const __bf16* __restrict__ vt, float* __restrict__ out) {
  __shared__ __bf16 ps[4][32][72];   // per-wave P tile [qrow][s]
  __shared__ float obuf[4][32][68];  // per-wave O partial
  __shared__ float msh[4][32], lsh[4][32];
  const int tid = threadIdx.x;
  const int lane = tid & 63;
  const int w = tid >> 6;
  const int l15 = lane & 15, lg = lane >> 4;
  const int b = blockIdx.y;
  const int qt = 63 - (int)blockIdx.x;
  const int q0 = qt * 32;
  const size_t bT = (size_t)b * NT;

  // Q fragments (already scaled by 1/8 in qb): B-operand of S^T = K·Q^T
  bf16x8 qf[2][2];
#pragma unroll
  for (int ct = 0; ct < 2; ++ct)
#pragma unroll
    for (int kh = 0; kh < 2; ++kh)
      qf[ct][kh] = *reinterpret_cast<const bf16x8*>(
          &qb[(bT + q0 + ct * 16 + l15) * NH + kh * 32 + lg * 8]);

  float m[2] = {-1e30f, -1e30f};
  float lsum[2] = {0.f, 0.f};
  f32x4 o[2][4];
#pragma unroll
  for (int i = 0; i < 2; ++i)
#pragma unroll
    for (int j = 0; j < 4; ++j) o[i][j] = (f32x4){0.f, 0.f, 0.f, 0.f};

  const int nch = qt / 2 + 1;
  for (int c = w; c < nch; c += 4) {
    const int s0 = c * 64;
    // K fragments (A-operand): row = s, contiguous h octet per lane
    bf16x8 kf[4][2];
#pragma unroll
    for (int st = 0; st < 4; ++st)
#pragma unroll
      for (int kh = 0; kh < 2; ++kh)
        kf[st][kh] = *reinterpret_cast<const bf16x8*>(
            &kb[(bT + s0 + st * 16 + l15) * NH + kh * 32 + lg * 8]);
    // S^T[64 s][32 q]
    f32x4 s[4][2];
#pragma unroll
    for (int st = 0; st < 4; ++st)
#pragma unroll
      for (int ct = 0; ct < 2; ++ct) s[st][ct] = (f32x4){0.f, 0.f, 0.f, 0.f};
#pragma unroll
    for (int st = 0; st < 4; ++st)
#pragma unroll
      for (int ct = 0; ct < 2; ++ct)
#pragma unroll
        for (int kh = 0; kh < 2; ++kh)
          s[st][ct] = __builtin_amdgcn_mfma_f32_16x16x32_bf16(kf[st][kh], qf[ct][kh], s[st][ct], 0, 0, 0);
    // causal mask, only on diagonal chunks. D: row(s)=(lg*4+r), col(q)=l15.
    if (s0 + 63 > q0) {
#pragma unroll
      for (int st = 0; st < 4; ++st)
#pragma unroll
        for (int ct = 0; ct < 2; ++ct) {
          int qg = q0 + ct * 16 + l15;
#pragma unroll
          for (int r = 0; r < 4; ++r) {
            int sg = s0 + st * 16 + lg * 4 + r;
            if (sg > qg) s[st][ct][r] = -1e30f;
          }
        }
    }
    // online softmax per q-half (ct); row stats via reg-max + xor16/32
    float scv[2];
#pragma unroll
    for (int ct = 0; ct < 2; ++ct) {
      float rmx = -1e30f;
#pragma unroll
      for (int st = 0; st < 4; ++st)
#pragma unroll
        for (int r = 0; r < 4; ++r) rmx = fmaxf(rmx, s[st][ct][r]);
      rmx = fmaxf(rmx, __shfl_xor(rmx, 16));
      rmx = fmaxf(rmx, __shfl_xor(rmx, 32));
      float mn = fmaxf(m[ct], rmx);
      float sc = __expf(m[ct] - mn);
      m[ct] = mn;
      float rs = 0.f;
#pragma unroll
      for (int st = 0; st < 4; ++st) {
        float p0 = __expf(s[st][ct][0] - mn);
        float p1 = __expf(s[st][ct][1] - mn);
        float p2 = __expf(s[st][ct][2] - mn);
        float p3 = __expf(s[st][ct][3] - mn);
        rs += (p0 + p1) + (p2 + p3);
        int sp = st * 16 + lg * 4;
        *reinterpret_cast<unsigned*>(&ps[w][ct * 16 + l15][sp]) = pack_bf2(p0, p1);
        *reinterpret_cast<unsigned*>(&ps[w][ct * 16 + l15][sp + 2]) = pack_bf2(p2, p3);
      }
      rs += __shfl_xor(rs, 16);
      rs += __shfl_xor(rs, 32);
      lsum[ct] = lsum[ct] * sc + rs;
      scv[ct] = sc;
    }
    // rescale O: factor for qrow rt*16 + lg*4 + r sourced from lane lg*4+r
#pragma unroll
    for (int rt = 0; rt < 2; ++rt)
#pragma unroll
      for (int r = 0; r < 4; ++r) {
        float fsc = __shfl(scv[rt], lg * 4 + r, 64);
#pragma unroll
        for (int ht = 0; ht < 4; ++ht) o[rt][ht][r] *= fsc;
      }
    // PV: A = P (from ps LDS), B = V (from vt: col=h, contiguous s octet)
    bf16x8 vf[4][2];
#pragma unroll
    for (int ht = 0; ht < 4; ++ht)
#pragma unroll
      for (int sh = 0; sh < 2; ++sh)
        vf[ht][sh] = *reinterpret_cast<const bf16x8*>(
            &vt[((size_t)b * NH + ht * 16 + l15) * NT + s0 + sh * 32 + lg * 8]);
#pragma unroll
    for (int rt = 0; rt < 2; ++rt) {
      bf16x8 pf[2];
#pragma unroll
      for (int sh = 0; sh < 2; ++sh)
        pf[sh] = *reinterpret_cast<const bf16x8*>(&ps[w][rt * 16 + l15][sh * 32 + lg * 8]);
#pragma unroll
      for (int ht = 0; ht < 4; ++ht)
#pragma unroll
        for (int sh = 0; sh < 2; ++sh)
          o[rt][ht] = __builtin_amdgcn_mfma_f32_16x16x32_bf16(pf[sh], vf[ht][sh], o[rt][ht], 0, 0, 0);
    }
  }

  // publish partials
  if (lg == 0) {
#pragma unroll
    for (int ct = 0; ct < 2; ++ct) {
      msh[w][ct * 16 + l15] = m[ct];
      lsh[w][ct * 16 + l15] = lsum[ct];
    }
  }
#pragma unroll
  for (int rt = 0; rt < 2; ++rt)
#pragma unroll
    for (int ht = 0; ht < 4; ++ht)
#pragma unroll
      for (int r = 0; r < 4; ++r)
        obuf[w][rt * 16 + lg * 4 + r][ht * 16 + l15] = o[rt][ht][r];
  __syncthreads();

  // combine the 4 wave-partials; write fp32 out
  {
    int qr = tid >> 3, h8 = (tid & 7) * 8;
    float m0 = msh[0][qr], m1 = msh[1][qr], m2 = msh[2][qr], m3 = msh[3][qr];
    float M = fmaxf(fmaxf(m0, m1), fmaxf(m2, m3));
    float e0 = __expf(m0 - M), e1 = __expf(m1 - M);
    float e2 = __expf(m2 - M), e3 = __expf(m3 - M);
    float L = e0 * lsh[0][qr] + e1 * lsh[1][qr] + e2 * lsh[2][qr] + e3 * lsh[3][qr];
    float inv = 1.f / L;
#pragma unroll
    for (int i = 0; i < 8; ++i) {
      int h = h8 + i;
      float v = e0 * obuf[0][qr][h] + e1 * obuf[1][qr][h] +
                e2 * obuf[2][qr][h] + e3 * obuf[3][qr][h];
      out[(bT + q0 + qr) * NH + h] = v * inv;
    }
  }
}

extern "C" void kernel_launch(void* const* d_in, const int* in_sizes, int n_in,
                              void* d_out, int out_size, void* d_ws, size_t ws_size,
                              hipStream_t stream) {
  const float* x  = (const float*)d_in[0];
  const float* Wq = (const float*)d_in[1];
  const float* Wk = (const float*)d_in[2];
  const float* Wv = (const float*)d_in[3];
  float* out = (float*)d_out;

  char* ws = (char*)d_ws;
  __bf16* wt = (__bf16*)(ws);                       // 192*1024*2 = 384 KB
  __bf16* qb = (__bf16*)(ws + 393216);              // 2 MB
  __bf16* kb = (__bf16*)(ws + 393216 + 2097152);    // 2 MB
  __bf16* vb = (__bf16*)(ws + 393216 + 2 * 2097152);// 2 MB
  __bf16* vt = (__bf16*)(ws + 393216 + 3 * 2097152);// 2 MB   (total ~8.4 MB)

  wt_kernel<<<dim3(48), dim3(256), 0, stream>>>(Wq, Wk, Wv, wt);
  qkv_mfma_kernel<<<dim3(256), dim3(512), 0, stream>>>(x, wt, qb, kb, vb);
  vt_kernel<<<dim3(32, 8), dim3(256), 0, stream>>>(vb, vt);
  attn_mfma_kernel<<<dim3(64, 8), dim3(256), 0, stream>>>(qb, kb, vt, out);
}

// Round 3
// 62.194 us; speedup vs baseline: 5.8059x; 1.0163x over previous
//
#include <hip/hip_runtime.h>

#define NB 8
#define NT 2048
#define NC 1024
#define NH 64

typedef __bf16 bf16x8 __attribute__((ext_vector_type(8)));
typedef float f32x4 __attribute__((ext_vector_type(4)));

static __device__ __forceinline__ float4 ldf4(const float* p) {
  return *reinterpret_cast<const float4*>(p);
}
static __device__ __forceinline__ unsigned pack_bf2(float a, float b) {
  unsigned short ua = __builtin_bit_cast(unsigned short, (__bf16)a);
  unsigned short ub = __builtin_bit_cast(unsigned short, (__bf16)b);
  return (unsigned)ua | ((unsigned)ub << 16);
}

// ---------------------------------------------------------------------------
// Kernel A: Wt[192][1024] bf16 = transpose+convert of Wq|Wk|Wv (fp32 [1024][64]).
// Grid: 48 blocks (3 mats x 16 k-tiles), 256 threads.
// ---------------------------------------------------------------------------
__global__ __launch_bounds__(256) void wt_kernel(
    const float* __restrict__ Wq, const float* __restrict__ Wk,
    const float* __restrict__ Wv, __bf16* __restrict__ wt) {
  __shared__ __bf16 tl[64][72];  // [h][k], rows 144B (16B-aligned, 2-way banks)
  const int tid = threadIdx.x;
  const int mat = blockIdx.x >> 4;
  const int k0 = (blockIdx.x & 15) * 64;
  const float* W = (mat == 0) ? Wq : (mat == 1) ? Wk : Wv;
#pragma unroll
  for (int it = 0; it < 4; ++it) {
    int f = tid + it * 256;
    int kk = f >> 4, c4 = (f & 15) * 4;
    float4 w = ldf4(&W[(k0 + kk) * NH + c4]);
    tl[c4 + 0][kk] = (__bf16)w.x;
    tl[c4 + 1][kk] = (__bf16)w.y;
    tl[c4 + 2][kk] = (__bf16)w.z;
    tl[c4 + 3][kk] = (__bf16)w.w;
  }
  __syncthreads();
#pragma unroll
  for (int it = 0; it < 2; ++it) {
    int f = tid + it * 256;
    int h = f >> 3, k8 = (f & 7) * 8;
    *reinterpret_cast<bf16x8*>(&wt[(mat * 64 + h) * NC + k0 + k8]) =
        *reinterpret_cast<const bf16x8*>(&tl[h][k8]);
  }
}

// ---------------------------------------------------------------------------
// Kernel B: q,k (bf16, row-major) and v^T (bf16, [b][h][t]) = x @ W via MFMA.
// 256 blocks x 512 thr (8 waves). BM=64, BN=192, BK=64 (2 MFMA k-steps).
// Wave w: rows (w>>2)*32 + [0,32), cols (w&3)*48 + [0,48).
// Reg-double-buffered staging. q pre-scaled by 1/8. v written transposed
// (acc r=0..3 are 4 consecutive t -> one 8B ushort4 store).
// ---------------------------------------------------------------------------
__global__ __launch_bounds__(512, 2) void qkv_mfma_kernel(
    const float* __restrict__ x, const __bf16* __restrict__ wt,
    __bf16* __restrict__ qb, __bf16* __restrict__ kb, __bf16* __restrict__ vt) {
  __shared__ __bf16 As[64][72];    // [row][k]
  __shared__ __bf16 Bs[192][72];   // [col][k]
  const int tid = threadIdx.x;
  const int lane = tid & 63;
  const int w = tid >> 6;
  const int row0 = blockIdx.x * 64;
  const int rsub = (w >> 2) * 32;
  const int csub = (w & 3) * 48;
  const int l15 = lane & 15, lg = lane >> 4;

  f32x4 acc[2][3];
#pragma unroll
  for (int i = 0; i < 2; ++i)
#pragma unroll
    for (int j = 0; j < 3; ++j) acc[i][j] = (f32x4){0.f, 0.f, 0.f, 0.f};

  float4 areg[2];
  bf16x8 breg[3];
  // prologue: prefetch chunk 0
#pragma unroll
  for (int it = 0; it < 2; ++it) {
    int f = tid + it * 512;
    int r = f >> 4, k4 = (f & 15) * 4;
    areg[it] = ldf4(&x[(row0 + r) * NC + k4]);
  }
#pragma unroll
  for (int it = 0; it < 3; ++it) {
    int f = tid + it * 512;
    int col = f >> 3, k8 = (f & 7) * 8;
    breg[it] = *reinterpret_cast<const bf16x8*>(&wt[col * NC + k8]);
  }

  for (int ch = 0; ch < 16; ++ch) {
    // write staged regs to LDS
#pragma unroll
    for (int it = 0; it < 2; ++it) {
      int f = tid + it * 512;
      int r = f >> 4, k4 = (f & 15) * 4;
      uint2 u = {pack_bf2(areg[it].x, areg[it].y), pack_bf2(areg[it].z, areg[it].w)};
      *reinterpret_cast<uint2*>(&As[r][k4]) = u;
    }
#pragma unroll
    for (int it = 0; it < 3; ++it) {
      int f = tid + it * 512;
      int col = f >> 3, k8 = (f & 7) * 8;
      *reinterpret_cast<bf16x8*>(&Bs[col][k8]) = breg[it];
    }
    __syncthreads();
    // prefetch chunk ch+1 (overlaps with MFMA below)
    if (ch < 15) {
      const int k0n = (ch + 1) * 64;
#pragma unroll
      for (int it = 0; it < 2; ++it) {
        int f = tid + it * 512;
        int r = f >> 4, k4 = (f & 15) * 4;
        areg[it] = ldf4(&x[(row0 + r) * NC + k0n + k4]);
      }
#pragma unroll
      for (int it = 0; it < 3; ++it) {
        int f = tid + it * 512;
        int col = f >> 3, k8 = (f & 7) * 8;
        breg[it] = *reinterpret_cast<const bf16x8*>(&wt[col * NC + k0n + k8]);
      }
    }
    // 2 MFMA k-steps over the staged BK=64
#pragma unroll
    for (int kk = 0; kk < 2; ++kk) {
      bf16x8 af[2], bfr[3];
#pragma unroll
      for (int rt = 0; rt < 2; ++rt)
        af[rt] = *reinterpret_cast<const bf16x8*>(&As[rsub + rt * 16 + l15][kk * 32 + lg * 8]);
#pragma unroll
      for (int nt = 0; nt < 3; ++nt)
        bfr[nt] = *reinterpret_cast<const bf16x8*>(&Bs[csub + nt * 16 + l15][kk * 32 + lg * 8]);
#pragma unroll
      for (int rt = 0; rt < 2; ++rt)
#pragma unroll
        for (int nt = 0; nt < 3; ++nt)
          acc[rt][nt] = __builtin_amdgcn_mfma_f32_16x16x32_bf16(af[rt], bfr[nt], acc[rt][nt], 0, 0, 0);
    }
    __syncthreads();
  }

  // epilogue: D layout col=l&15, row=(l>>4)*4+reg. mat uniform per (w,nt).
#pragma unroll
  for (int rt = 0; rt < 2; ++rt) {
#pragma unroll
    for (int nt = 0; nt < 3; ++nt) {
      int colb = csub + nt * 16 + l15;
      int mat = (csub + nt * 16) >> 6;  // wave-uniform
      int h = colb & 63;
      if (mat == 0) {
#pragma unroll
        for (int r = 0; r < 4; ++r) {
          int row = row0 + rsub + rt * 16 + lg * 4 + r;
          qb[row * NH + h] = (__bf16)(acc[rt][nt][r] * 0.125f);  // pre-scale q
        }
      } else if (mat == 1) {
#pragma unroll
        for (int r = 0; r < 4; ++r) {
          int row = row0 + rsub + rt * 16 + lg * 4 + r;
          kb[row * NH + h] = (__bf16)acc[rt][nt][r];
        }
      } else {
        // v -> transposed store: 4 consecutive t as one 8B packed store
        int bb = row0 >> 11;                               // batch
        int t0l = (row0 & (NT - 1)) + rsub + rt * 16 + lg * 4;
        ushort4 pk;
        pk.x = __builtin_bit_cast(unsigned short, (__bf16)acc[rt][nt][0]);
        pk.y = __builtin_bit_cast(unsigned short, (__bf16)acc[rt][nt][1]);
        pk.z = __builtin_bit_cast(unsigned short, (__bf16)acc[rt][nt][2]);
        pk.w = __builtin_bit_cast(unsigned short, (__bf16)acc[rt][nt][3]);
        *reinterpret_cast<ushort4*>(&vt[((size_t)bb * NH + h) * NT + t0l]) = pk;
      }
    }
  }
}

// ---------------------------------------------------------------------------
// Kernel C: causal flash attention via MFMA, intra-block KV split.
// Grid: dim3(64, 8) (qt reversed so heavy tiles launch first), 256 thr = 4 waves.
// Each wave: all 32 q-rows, KV chunks c = w, w+4, ... (KVBLK=64).
// S^T = mfma(K, Q): per-lane row-local softmax; P via wave-private LDS; PV via
// vT global frags (prefetched 1 chunk ahead). End: 4-way LDS combine.
// ---------------------------------------------------------------------------
__global__ __launch_bounds__(256, 2) void attn_mfma_kernel(
    const __bf16* __restrict__ qb, const __bf16* __restrict__ kb,
    const __bf16* __restrict__ vt, float* __restrict__ out) {
  __shared__ __bf16 ps[4][32][72];   // per-wave P tile [qrow][s]
  __shared__ float obuf[4][32][68];  // per-wave O partial
  __shared__ float msh[4][32], lsh[4][32];
  const int tid = threadIdx.x;
  const int lane = tid & 63;
  const int w = tid >> 6;
  const int l15 = lane & 15, lg = lane >> 4;
  const int b = blockIdx.y;
  const int qt = 63 - (int)blockIdx.x;
  const int q0 = qt * 32;
  const size_t bT = (size_t)b * NT;

  // Q fragments (already scaled by 1/8 in qb): B-operand of S^T = K·Q^T
  bf16x8 qf[2][2];
#pragma unroll
  for (int ct = 0; ct < 2; ++ct)
#pragma unroll
    for (int kh = 0; kh < 2; ++kh)
      qf[ct][kh] = *reinterpret_cast<const bf16x8*>(
          &qb[(bT + q0 + ct * 16 + l15) * NH + kh * 32 + lg * 8]);

  float m[2] = {-1e30f, -1e30f};
  float lsum[2] = {0.f, 0.f};
  f32x4 o[2][4];
#pragma unroll
  for (int i = 0; i < 2; ++i)
#pragma unroll
    for (int j = 0; j < 4; ++j) o[i][j] = (f32x4){0.f, 0.f, 0.f, 0.f};

  const int nch = qt / 2 + 1;
  bf16x8 kf[4][2], vf[4][2];
  if (w < nch) {
    const int s0 = w * 64;
#pragma unroll
    for (int st = 0; st < 4; ++st)
#pragma unroll
      for (int kh = 0; kh < 2; ++kh)
        kf[st][kh] = *reinterpret_cast<const bf16x8*>(
            &kb[(bT + s0 + st * 16 + l15) * NH + kh * 32 + lg * 8]);
#pragma unroll
    for (int ht = 0; ht < 4; ++ht)
#pragma unroll
      for (int sh = 0; sh < 2; ++sh)
        vf[ht][sh] = *reinterpret_cast<const bf16x8*>(
            &vt[((size_t)b * NH + ht * 16 + l15) * NT + s0 + sh * 32 + lg * 8]);
  }

  for (int c = w; c < nch; c += 4) {
    const int s0 = c * 64;
    // S^T[64 s][32 q]
    f32x4 s[4][2];
#pragma unroll
    for (int st = 0; st < 4; ++st)
#pragma unroll
      for (int ct = 0; ct < 2; ++ct) s[st][ct] = (f32x4){0.f, 0.f, 0.f, 0.f};
#pragma unroll
    for (int st = 0; st < 4; ++st)
#pragma unroll
      for (int ct = 0; ct < 2; ++ct)
#pragma unroll
        for (int kh = 0; kh < 2; ++kh)
          s[st][ct] = __builtin_amdgcn_mfma_f32_16x16x32_bf16(kf[st][kh], qf[ct][kh], s[st][ct], 0, 0, 0);

    // prefetch next chunk's K/V frags (overlaps softmax + PV below)
    const int cn = c + 4;
    bf16x8 kfn[4][2], vfn[4][2];
    if (cn < nch) {
      const int sn = cn * 64;
#pragma unroll
      for (int st = 0; st < 4; ++st)
#pragma unroll
        for (int kh = 0; kh < 2; ++kh)
          kfn[st][kh] = *reinterpret_cast<const bf16x8*>(
              &kb[(bT + sn + st * 16 + l15) * NH + kh * 32 + lg * 8]);
#pragma unroll
      for (int ht = 0; ht < 4; ++ht)
#pragma unroll
        for (int sh = 0; sh < 2; ++sh)
          vfn[ht][sh] = *reinterpret_cast<const bf16x8*>(
              &vt[((size_t)b * NH + ht * 16 + l15) * NT + sn + sh * 32 + lg * 8]);
    }

    // causal mask, only on diagonal chunks. D: row(s)=(lg*4+r), col(q)=l15.
    if (s0 + 63 > q0) {
#pragma unroll
      for (int st = 0; st < 4; ++st)
#pragma unroll
        for (int ct = 0; ct < 2; ++ct) {
          int qg = q0 + ct * 16 + l15;
#pragma unroll
          for (int r = 0; r < 4; ++r) {
            int sg = s0 + st * 16 + lg * 4 + r;
            if (sg > qg) s[st][ct][r] = -1e30f;
          }
        }
    }
    // online softmax per q-half (ct); row stats via reg-max + xor16/32
    float scv[2];
#pragma unroll
    for (int ct = 0; ct < 2; ++ct) {
      float rmx = -1e30f;
#pragma unroll
      for (int st = 0; st < 4; ++st)
#pragma unroll
        for (int r = 0; r < 4; ++r) rmx = fmaxf(rmx, s[st][ct][r]);
      rmx = fmaxf(rmx, __shfl_xor(rmx, 16));
      rmx = fmaxf(rmx, __shfl_xor(rmx, 32));
      float mn = fmaxf(m[ct], rmx);
      float sc = __expf(m[ct] - mn);
      m[ct] = mn;
      float rs = 0.f;
#pragma unroll
      for (int st = 0; st < 4; ++st) {
        float p0 = __expf(s[st][ct][0] - mn);
        float p1 = __expf(s[st][ct][1] - mn);
        float p2 = __expf(s[st][ct][2] - mn);
        float p3 = __expf(s[st][ct][3] - mn);
        rs += (p0 + p1) + (p2 + p3);
        int sp = st * 16 + lg * 4;
        *reinterpret_cast<unsigned*>(&ps[w][ct * 16 + l15][sp]) = pack_bf2(p0, p1);
        *reinterpret_cast<unsigned*>(&ps[w][ct * 16 + l15][sp + 2]) = pack_bf2(p2, p3);
      }
      rs += __shfl_xor(rs, 16);
      rs += __shfl_xor(rs, 32);
      lsum[ct] = lsum[ct] * sc + rs;
      scv[ct] = sc;
    }
    // rescale O: factor for qrow rt*16 + lg*4 + r sourced from lane lg*4+r
#pragma unroll
    for (int rt = 0; rt < 2; ++rt)
#pragma unroll
      for (int r = 0; r < 4; ++r) {
        float fsc = __shfl(scv[rt], lg * 4 + r, 64);
#pragma unroll
        for (int ht = 0; ht < 4; ++ht) o[rt][ht][r] *= fsc;
      }
    // PV: A = P (from ps LDS), B = V (current vf)
#pragma unroll
    for (int rt = 0; rt < 2; ++rt) {
      bf16x8 pf[2];
#pragma unroll
      for (int sh = 0; sh < 2; ++sh)
        pf[sh] = *reinterpret_cast<const bf16x8*>(&ps[w][rt * 16 + l15][sh * 32 + lg * 8]);
#pragma unroll
      for (int ht = 0; ht < 4; ++ht)
#pragma unroll
        for (int sh = 0; sh < 2; ++sh)
          o[rt][ht] = __builtin_amdgcn_mfma_f32_16x16x32_bf16(pf[sh], vf[ht][sh], o[rt][ht], 0, 0, 0);
    }
    // rotate prefetched frags in
    if (cn < nch) {
#pragma unroll
      for (int st = 0; st < 4; ++st)
#pragma unroll
        for (int kh = 0; kh < 2; ++kh) kf[st][kh] = kfn[st][kh];
#pragma unroll
      for (int ht = 0; ht < 4; ++ht)
#pragma unroll
        for (int sh = 0; sh < 2; ++sh) vf[ht][sh] = vfn[ht][sh];
    }
  }

  // publish partials
  if (lg == 0) {
#pragma unroll
    for (int ct = 0; ct < 2; ++ct) {
      msh[w][ct * 16 + l15] = m[ct];
      lsh[w][ct * 16 + l15] = lsum[ct];
    }
  }
#pragma unroll
  for (int rt = 0; rt < 2; ++rt)
#pragma unroll
    for (int ht = 0; ht < 4; ++ht)
#pragma unroll
      for (int r = 0; r < 4; ++r)
        obuf[w][rt * 16 + lg * 4 + r][ht * 16 + l15] = o[rt][ht][r];
  __syncthreads();

  // combine the 4 wave-partials; write fp32 out
  {
    int qr = tid >> 3, h8 = (tid & 7) * 8;
    float m0 = msh[0][qr], m1 = msh[1][qr], m2 = msh[2][qr], m3 = msh[3][qr];
    float M = fmaxf(fmaxf(m0, m1), fmaxf(m2, m3));
    float e0 = __expf(m0 - M), e1 = __expf(m1 - M);
    float e2 = __expf(m2 - M), e3 = __expf(m3 - M);
    float L = e0 * lsh[0][qr] + e1 * lsh[1][qr] + e2 * lsh[2][qr] + e3 * lsh[3][qr];
    float inv = 1.f / L;
#pragma unroll
    for (int i = 0; i < 8; ++i) {
      int h = h8 + i;
      float v = e0 * obuf[0][qr][h] + e1 * obuf[1][qr][h] +
                e2 * obuf[2][qr][h] + e3 * obuf[3][qr][h];
      out[(bT + q0 + qr) * NH + h] = v * inv;
    }
  }
}

extern "C" void kernel_launch(void* const* d_in, const int* in_sizes, int n_in,
                              void* d_out, int out_size, void* d_ws, size_t ws_size,
                              hipStream_t stream) {
  const float* x  = (const float*)d_in[0];
  const float* Wq = (const float*)d_in[1];
  const float* Wk = (const float*)d_in[2];
  const float* Wv = (const float*)d_in[3];
  float* out = (float*)d_out;

  char* ws = (char*)d_ws;
  __bf16* wt = (__bf16*)(ws);                        // 192*1024*2 = 384 KB
  __bf16* qb = (__bf16*)(ws + 393216);               // 2 MB
  __bf16* kb = (__bf16*)(ws + 393216 + 2097152);     // 2 MB
  __bf16* vt = (__bf16*)(ws + 393216 + 2 * 2097152); // 2 MB  (total ~6.7 MB)

  wt_kernel<<<dim3(48), dim3(256), 0, stream>>>(Wq, Wk, Wv, wt);
  qkv_mfma_kernel<<<dim3(256), dim3(512), 0, stream>>>(x, wt, qb, kb, vt);
  attn_mfma_kernel<<<dim3(64, 8), dim3(256), 0, stream>>>(qb, kb, vt, out);
}

// Round 4
// 48.059 us; speedup vs baseline: 7.5135x; 1.2941x over previous
//
#include <hip/hip_runtime.h>

#define NB 8
#define NT 2048
#define NC 1024
#define NH 64

typedef __bf16 bf16x8 __attribute__((ext_vector_type(8)));
typedef float f32x4 __attribute__((ext_vector_type(4)));

static __device__ __forceinline__ float4 ldf4(const float* p) {
  return *reinterpret_cast<const float4*>(p);
}
static __device__ __forceinline__ unsigned pack_bf2(float a, float b) {
  unsigned short ua = __builtin_bit_cast(unsigned short, (__bf16)a);
  unsigned short ub = __builtin_bit_cast(unsigned short, (__bf16)b);
  return (unsigned)ua | ((unsigned)ub << 16);
}

// ---------------------------------------------------------------------------
// Kernel A: Wt[192][1024] bf16 = transpose+convert of Wq|Wk|Wv (fp32 [1024][64]).
// ---------------------------------------------------------------------------
__global__ __launch_bounds__(256) void wt_kernel(
    const float* __restrict__ Wq, const float* __restrict__ Wk,
    const float* __restrict__ Wv, __bf16* __restrict__ wt) {
  __shared__ __bf16 tl[64][72];
  const int tid = threadIdx.x;
  const int mat = blockIdx.x >> 4;
  const int k0 = (blockIdx.x & 15) * 64;
  const float* W = (mat == 0) ? Wq : (mat == 1) ? Wk : Wv;
#pragma unroll
  for (int it = 0; it < 4; ++it) {
    int f = tid + it * 256;
    int kk = f >> 4, c4 = (f & 15) * 4;
    float4 w = ldf4(&W[(k0 + kk) * NH + c4]);
    tl[c4 + 0][kk] = (__bf16)w.x;
    tl[c4 + 1][kk] = (__bf16)w.y;
    tl[c4 + 2][kk] = (__bf16)w.z;
    tl[c4 + 3][kk] = (__bf16)w.w;
  }
  __syncthreads();
#pragma unroll
  for (int it = 0; it < 2; ++it) {
    int f = tid + it * 256;
    int h = f >> 3, k8 = (f & 7) * 8;
    *reinterpret_cast<bf16x8*>(&wt[(mat * 64 + h) * NC + k0 + k8]) =
        *reinterpret_cast<const bf16x8*>(&tl[h][k8]);
  }
}

// ---------------------------------------------------------------------------
// Kernel B: q,k (bf16 row-major) and v^T (bf16 [b][h][t]) = x @ W via MFMA.
// BM=32, BN=192, BK=64. 512 blocks x 256 thr (4 waves) -> 2 blocks/CU so
// independent blocks overlap at barriers. Wave w: rows [0,32), cols w*48+[0,48).
// v epilogue goes through LDS transpose -> coalesced 16B stores.
// ---------------------------------------------------------------------------
__global__ __launch_bounds__(256, 2) void qkv_mfma_kernel(
    const float* __restrict__ x, const __bf16* __restrict__ wt,
    __bf16* __restrict__ qb, __bf16* __restrict__ kb, __bf16* __restrict__ vt) {
  __shared__ __bf16 As[32][72];    // [row][k]
  __shared__ __bf16 Bs[192][72];   // [col][k]
  __shared__ __bf16 vls[64][40];   // [h][t_local] for v transpose
  const int tid = threadIdx.x;
  const int lane = tid & 63;
  const int w = tid >> 6;          // 0..3
  const int row0 = blockIdx.x * 32;
  const int csub = w * 48;
  const int l15 = lane & 15, lg = lane >> 4;

  f32x4 acc[2][3];
#pragma unroll
  for (int i = 0; i < 2; ++i)
#pragma unroll
    for (int j = 0; j < 3; ++j) acc[i][j] = (f32x4){0.f, 0.f, 0.f, 0.f};

  float4 areg[2];
  bf16x8 breg[6];
  // prologue: prefetch chunk 0
#pragma unroll
  for (int it = 0; it < 2; ++it) {
    int f = tid + it * 256;
    int r = f >> 4, k4 = (f & 15) * 4;
    areg[it] = ldf4(&x[(row0 + r) * NC + k4]);
  }
#pragma unroll
  for (int it = 0; it < 6; ++it) {
    int f = tid + it * 256;
    int col = f >> 3, k8 = (f & 7) * 8;
    breg[it] = *reinterpret_cast<const bf16x8*>(&wt[col * NC + k8]);
  }

  for (int ch = 0; ch < 16; ++ch) {
    // write staged regs to LDS
#pragma unroll
    for (int it = 0; it < 2; ++it) {
      int f = tid + it * 256;
      int r = f >> 4, k4 = (f & 15) * 4;
      uint2 u = {pack_bf2(areg[it].x, areg[it].y), pack_bf2(areg[it].z, areg[it].w)};
      *reinterpret_cast<uint2*>(&As[r][k4]) = u;
    }
#pragma unroll
    for (int it = 0; it < 6; ++it) {
      int f = tid + it * 256;
      int col = f >> 3, k8 = (f & 7) * 8;
      *reinterpret_cast<bf16x8*>(&Bs[col][k8]) = breg[it];
    }
    __syncthreads();
    // prefetch chunk ch+1 (overlaps with MFMA below)
    if (ch < 15) {
      const int k0n = (ch + 1) * 64;
#pragma unroll
      for (int it = 0; it < 2; ++it) {
        int f = tid + it * 256;
        int r = f >> 4, k4 = (f & 15) * 4;
        areg[it] = ldf4(&x[(row0 + r) * NC + k0n + k4]);
      }
#pragma unroll
      for (int it = 0; it < 6; ++it) {
        int f = tid + it * 256;
        int col = f >> 3, k8 = (f & 7) * 8;
        breg[it] = *reinterpret_cast<const bf16x8*>(&wt[col * NC + k0n + k8]);
      }
    }
    // 2 MFMA k-steps over the staged BK=64
#pragma unroll
    for (int kk = 0; kk < 2; ++kk) {
      bf16x8 af[2], bfr[3];
#pragma unroll
      for (int rt = 0; rt < 2; ++rt)
        af[rt] = *reinterpret_cast<const bf16x8*>(&As[rt * 16 + l15][kk * 32 + lg * 8]);
#pragma unroll
      for (int nt = 0; nt < 3; ++nt)
        bfr[nt] = *reinterpret_cast<const bf16x8*>(&Bs[csub + nt * 16 + l15][kk * 32 + lg * 8]);
#pragma unroll
      for (int rt = 0; rt < 2; ++rt)
#pragma unroll
        for (int nt = 0; nt < 3; ++nt)
          acc[rt][nt] = __builtin_amdgcn_mfma_f32_16x16x32_bf16(af[rt], bfr[nt], acc[rt][nt], 0, 0, 0);
    }
    __syncthreads();
  }

  // epilogue: D layout col=l&15, row=(l>>4)*4+reg. mat uniform per (w,nt).
#pragma unroll
  for (int rt = 0; rt < 2; ++rt) {
#pragma unroll
    for (int nt = 0; nt < 3; ++nt) {
      int colbase = csub + nt * 16;   // wave-uniform, multiple of 16
      int mat = colbase >> 6;
      int h = (colbase & 63) + l15;
      if (mat == 0) {
#pragma unroll
        for (int r = 0; r < 4; ++r) {
          int row = row0 + rt * 16 + lg * 4 + r;
          qb[row * NH + h] = (__bf16)(acc[rt][nt][r] * 0.125f);  // pre-scale q
        }
      } else if (mat == 1) {
#pragma unroll
        for (int r = 0; r < 4; ++r) {
          int row = row0 + rt * 16 + lg * 4 + r;
          kb[row * NH + h] = (__bf16)acc[rt][nt][r];
        }
      } else {
        // v: stage transposed into LDS (4 consecutive t = one 8B write)
        ushort4 pk;
        pk.x = __builtin_bit_cast(unsigned short, (__bf16)acc[rt][nt][0]);
        pk.y = __builtin_bit_cast(unsigned short, (__bf16)acc[rt][nt][1]);
        pk.z = __builtin_bit_cast(unsigned short, (__bf16)acc[rt][nt][2]);
        pk.w = __builtin_bit_cast(unsigned short, (__bf16)acc[rt][nt][3]);
        *reinterpret_cast<ushort4*>(&vls[h][rt * 16 + lg * 4]) = pk;
      }
    }
  }
  __syncthreads();
  // cooperative coalesced v^T store: 64 h x 32 t, one 16B store per thread
  {
    int h = tid >> 2, t8 = (tid & 3) * 8;
    int bb = row0 >> 11;
    int t0l = row0 & (NT - 1);
    *reinterpret_cast<bf16x8*>(&vt[((size_t)bb * NH + h) * NT + t0l + t8]) =
        *reinterpret_cast<const bf16x8*>(&vls[h][t8]);
  }
}

// ---------------------------------------------------------------------------
// Kernel C: causal flash attention via MFMA, intra-block KV split.
// Grid: dim3(64, 8); qt = (y<4) ? 63-x : x so the two blocks sharing a CU
// (L and L+256) have complementary work. 256 thr = 4 waves; wave w handles
// KV chunks c = w, w+4, ... (KVBLK=64). setprio(1) around MFMA clusters.
// ---------------------------------------------------------------------------
__global__ __launch_bounds__(256, 2) void attn_mfma_kernel(
    const __bf16* __restrict__ qb, const __bf16* __restrict__ kb,
    const __bf16* __restrict__ vt, float* __restrict__ out) {
  __shared__ __bf16 ps[4][32][72];   // per-wave P tile [qrow][s]
  __shared__ float obuf[4][32][68];  // per-wave O partial
  __shared__ float msh[4][32], lsh[4][32];
  const int tid = threadIdx.x;
  const int lane = tid & 63;
  const int w = tid >> 6;
  const int l15 = lane & 15, lg = lane >> 4;
  const int b = blockIdx.y;
  const int qt = (blockIdx.y < 4) ? (63 - (int)blockIdx.x) : (int)blockIdx.x;
  const int q0 = qt * 32;
  const size_t bT = (size_t)b * NT;

  // Q fragments (already scaled by 1/8 in qb): B-operand of S^T = K·Q^T
  bf16x8 qf[2][2];
#pragma unroll
  for (int ct = 0; ct < 2; ++ct)
#pragma unroll
    for (int kh = 0; kh < 2; ++kh)
      qf[ct][kh] = *reinterpret_cast<const bf16x8*>(
          &qb[(bT + q0 + ct * 16 + l15) * NH + kh * 32 + lg * 8]);

  float m[2] = {-1e30f, -1e30f};
  float lsum[2] = {0.f, 0.f};
  f32x4 o[2][4];
#pragma unroll
  for (int i = 0; i < 2; ++i)
#pragma unroll
    for (int j = 0; j < 4; ++j) o[i][j] = (f32x4){0.f, 0.f, 0.f, 0.f};

  const int nch = qt / 2 + 1;
  bf16x8 kf[4][2], vf[4][2];
  if (w < nch) {
    const int s0 = w * 64;
#pragma unroll
    for (int st = 0; st < 4; ++st)
#pragma unroll
      for (int kh = 0; kh < 2; ++kh)
        kf[st][kh] = *reinterpret_cast<const bf16x8*>(
            &kb[(bT + s0 + st * 16 + l15) * NH + kh * 32 + lg * 8]);
#pragma unroll
    for (int ht = 0; ht < 4; ++ht)
#pragma unroll
      for (int sh = 0; sh < 2; ++sh)
        vf[ht][sh] = *reinterpret_cast<const bf16x8*>(
            &vt[((size_t)b * NH + ht * 16 + l15) * NT + s0 + sh * 32 + lg * 8]);
  }

  for (int c = w; c < nch; c += 4) {
    const int s0 = c * 64;
    // S^T[64 s][32 q]
    f32x4 s[4][2];
#pragma unroll
    for (int st = 0; st < 4; ++st)
#pragma unroll
      for (int ct = 0; ct < 2; ++ct) s[st][ct] = (f32x4){0.f, 0.f, 0.f, 0.f};
    __builtin_amdgcn_s_setprio(1);
#pragma unroll
    for (int st = 0; st < 4; ++st)
#pragma unroll
      for (int ct = 0; ct < 2; ++ct)
#pragma unroll
        for (int kh = 0; kh < 2; ++kh)
          s[st][ct] = __builtin_amdgcn_mfma_f32_16x16x32_bf16(kf[st][kh], qf[ct][kh], s[st][ct], 0, 0, 0);
    __builtin_amdgcn_s_setprio(0);

    // prefetch next chunk's K/V frags (overlaps softmax + PV below)
    const int cn = c + 4;
    bf16x8 kfn[4][2], vfn[4][2];
    if (cn < nch) {
      const int sn = cn * 64;
#pragma unroll
      for (int st = 0; st < 4; ++st)
#pragma unroll
        for (int kh = 0; kh < 2; ++kh)
          kfn[st][kh] = *reinterpret_cast<const bf16x8*>(
              &kb[(bT + sn + st * 16 + l15) * NH + kh * 32 + lg * 8]);
#pragma unroll
      for (int ht = 0; ht < 4; ++ht)
#pragma unroll
        for (int sh = 0; sh < 2; ++sh)
          vfn[ht][sh] = *reinterpret_cast<const bf16x8*>(
              &vt[((size_t)b * NH + ht * 16 + l15) * NT + sn + sh * 32 + lg * 8]);
    }

    // causal mask, only on diagonal chunks. D: row(s)=(lg*4+r), col(q)=l15.
    if (s0 + 63 > q0) {
#pragma unroll
      for (int st = 0; st < 4; ++st)
#pragma unroll
        for (int ct = 0; ct < 2; ++ct) {
          int qg = q0 + ct * 16 + l15;
#pragma unroll
          for (int r = 0; r < 4; ++r) {
            int sg = s0 + st * 16 + lg * 4 + r;
            if (sg > qg) s[st][ct][r] = -1e30f;
          }
        }
    }
    // online softmax per q-half (ct); row stats via reg-max + xor16/32
    float scv[2];
#pragma unroll
    for (int ct = 0; ct < 2; ++ct) {
      float rmx = -1e30f;
#pragma unroll
      for (int st = 0; st < 4; ++st)
#pragma unroll
        for (int r = 0; r < 4; ++r) rmx = fmaxf(rmx, s[st][ct][r]);
      rmx = fmaxf(rmx, __shfl_xor(rmx, 16));
      rmx = fmaxf(rmx, __shfl_xor(rmx, 32));
      float mn = fmaxf(m[ct], rmx);
      float sc = __expf(m[ct] - mn);
      m[ct] = mn;
      float rs = 0.f;
#pragma unroll
      for (int st = 0; st < 4; ++st) {
        float p0 = __expf(s[st][ct][0] - mn);
        float p1 = __expf(s[st][ct][1] - mn);
        float p2 = __expf(s[st][ct][2] - mn);
        float p3 = __expf(s[st][ct][3] - mn);
        rs += (p0 + p1) + (p2 + p3);
        int sp = st * 16 + lg * 4;
        *reinterpret_cast<unsigned*>(&ps[w][ct * 16 + l15][sp]) = pack_bf2(p0, p1);
        *reinterpret_cast<unsigned*>(&ps[w][ct * 16 + l15][sp + 2]) = pack_bf2(p2, p3);
      }
      rs += __shfl_xor(rs, 16);
      rs += __shfl_xor(rs, 32);
      lsum[ct] = lsum[ct] * sc + rs;
      scv[ct] = sc;
    }
    // rescale O: factor for qrow rt*16 + lg*4 + r sourced from lane lg*4+r
#pragma unroll
    for (int rt = 0; rt < 2; ++rt)
#pragma unroll
      for (int r = 0; r < 4; ++r) {
        float fsc = __shfl(scv[rt], lg * 4 + r, 64);
#pragma unroll
        for (int ht = 0; ht < 4; ++ht) o[rt][ht][r] *= fsc;
      }
    // PV: A = P (from ps LDS), B = V (current vf)
    __builtin_amdgcn_s_setprio(1);
#pragma unroll
    for (int rt = 0; rt < 2; ++rt) {
      bf16x8 pf[2];
#pragma unroll
      for (int sh = 0; sh < 2; ++sh)
        pf[sh] = *reinterpret_cast<const bf16x8*>(&ps[w][rt * 16 + l15][sh * 32 + lg * 8]);
#pragma unroll
      for (int ht = 0; ht < 4; ++ht)
#pragma unroll
        for (int sh = 0; sh < 2; ++sh)
          o[rt][ht] = __builtin_amdgcn_mfma_f32_16x16x32_bf16(pf[sh], vf[ht][sh], o[rt][ht], 0, 0, 0);
    }
    __builtin_amdgcn_s_setprio(0);
    // rotate prefetched frags in
    if (cn < nch) {
#pragma unroll
      for (int st = 0; st < 4; ++st)
#pragma unroll
        for (int kh = 0; kh < 2; ++kh) kf[st][kh] = kfn[st][kh];
#pragma unroll
      for (int ht = 0; ht < 4; ++ht)
#pragma unroll
        for (int sh = 0; sh < 2; ++sh) vf[ht][sh] = vfn[ht][sh];
    }
  }

  // publish partials
  if (lg == 0) {
#pragma unroll
    for (int ct = 0; ct < 2; ++ct) {
      msh[w][ct * 16 + l15] = m[ct];
      lsh[w][ct * 16 + l15] = lsum[ct];
    }
  }
#pragma unroll
  for (int rt = 0; rt < 2; ++rt)
#pragma unroll
    for (int ht = 0; ht < 4; ++ht)
#pragma unroll
      for (int r = 0; r < 4; ++r)
        obuf[w][rt * 16 + lg * 4 + r][ht * 16 + l15] = o[rt][ht][r];
  __syncthreads();

  // combine the 4 wave-partials; write fp32 out
  {
    int qr = tid >> 3, h8 = (tid & 7) * 8;
    float m0 = msh[0][qr], m1 = msh[1][qr], m2 = msh[2][qr], m3 = msh[3][qr];
    float M = fmaxf(fmaxf(m0, m1), fmaxf(m2, m3));
    float e0 = __expf(m0 - M), e1 = __expf(m1 - M);
    float e2 = __expf(m2 - M), e3 = __expf(m3 - M);
    float L = e0 * lsh[0][qr] + e1 * lsh[1][qr] + e2 * lsh[2][qr] + e3 * lsh[3][qr];
    float inv = 1.f / L;
#pragma unroll
    for (int i = 0; i < 8; ++i) {
      int h = h8 + i;
      float v = e0 * obuf[0][qr][h] + e1 * obuf[1][qr][h] +
                e2 * obuf[2][qr][h] + e3 * obuf[3][qr][h];
      out[(bT + q0 + qr) * NH + h] = v * inv;
    }
  }
}

extern "C" void kernel_launch(void* const* d_in, const int* in_sizes, int n_in,
                              void* d_out, int out_size, void* d_ws, size_t ws_size,
                              hipStream_t stream) {
  const float* x  = (const float*)d_in[0];
  const float* Wq = (const float*)d_in[1];
  const float* Wk = (const float*)d_in[2];
  const float* Wv = (const float*)d_in[3];
  float* out = (float*)d_out;

  char* ws = (char*)d_ws;
  __bf16* wt = (__bf16*)(ws);                        // 192*1024*2 = 384 KB
  __bf16* qb = (__bf16*)(ws + 393216);               // 2 MB
  __bf16* kb = (__bf16*)(ws + 393216 + 2097152);     // 2 MB
  __bf16* vt = (__bf16*)(ws + 393216 + 2 * 2097152); // 2 MB  (total ~6.7 MB)

  wt_kernel<<<dim3(48), dim3(256), 0, stream>>>(Wq, Wk, Wv, wt);
  qkv_mfma_kernel<<<dim3(512), dim3(256), 0, stream>>>(x, wt, qb, kb, vt);
  attn_mfma_kernel<<<dim3(64, 8), dim3(256), 0, stream>>>(qb, kb, vt, out);
}